// Round 3
// baseline (620.091 us; speedup 1.0000x reference)
//
#include <hip/hip_runtime.h>
#include <hip/hip_bf16.h>

#define N_NODES 100000
#define N_EDGES 1600000
#define F_INPUT 256
#define H1DIM 64
#define H2DIM 128
#define BATCH 4096

// ---------------- degree / dis ----------------
__global__ void k_deg(const int* __restrict__ dst, const float* __restrict__ ew,
                      float* __restrict__ degw, int* __restrict__ cnt) {
    int e = blockIdx.x * blockDim.x + threadIdx.x;
    if (e >= N_EDGES) return;
    int d = dst[e];
    atomicAdd(&cnt[d], 1);
    atomicAdd(&degw[d], ew[e]);
}

__global__ void k_dis(float* __restrict__ degw) {
    int n = blockIdx.x * blockDim.x + threadIdx.x;
    if (n >= N_NODES) return;
    degw[n] = rsqrtf(degw[n] + 1.0f);  // self-loop weight 1; deg+1 > 0 always
}

// ---------------- prefix scan (3 kernels) ----------------
__global__ void k_scan1(const int* __restrict__ cnt, int* __restrict__ rowptr,
                        int* __restrict__ bsums) {
    __shared__ int sh[256];
    int base = blockIdx.x * 1024;
    int t = threadIdx.x;
    int i0 = base + t * 4;
    int v[4];
#pragma unroll
    for (int j = 0; j < 4; ++j) {
        int i = i0 + j;
        v[j] = (i < N_NODES) ? cnt[i] : 0;
    }
    int s = v[0] + v[1] + v[2] + v[3];
    sh[t] = s;
    __syncthreads();
    for (int off = 1; off < 256; off <<= 1) {
        int xv = (t >= off) ? sh[t - off] : 0;
        __syncthreads();
        sh[t] += xv;
        __syncthreads();
    }
    int ex = sh[t] - s;  // exclusive prefix of this thread's chunk
    if (t == 255) bsums[blockIdx.x] = sh[255];
    int run = ex;
#pragma unroll
    for (int j = 0; j < 4; ++j) {
        int i = i0 + j;
        if (i < N_NODES) rowptr[i] = run;
        run += v[j];
    }
}

__global__ void k_scan2(int* __restrict__ bsums, int nb) {
    if (blockIdx.x == 0 && threadIdx.x == 0) {
        int run = 0;
        for (int i = 0; i < nb; ++i) { int v = bsums[i]; bsums[i] = run; run += v; }
    }
}

__global__ void k_scan3(int* __restrict__ rowptr, const int* __restrict__ bsums,
                        int* __restrict__ woff) {
    int i = blockIdx.x * blockDim.x + threadIdx.x;
    if (i == 0) rowptr[N_NODES] = N_EDGES;
    if (i >= N_NODES) return;
    int v = rowptr[i] + bsums[i >> 10];
    rowptr[i] = v;
    woff[i] = v;
}

// ---------------- CSR fill (src + norm, sorted by dst) ----------------
__global__ void k_fill(const int* __restrict__ src, const int* __restrict__ dst,
                       const float* __restrict__ ew, const float* __restrict__ dis,
                       int* __restrict__ woff, int* __restrict__ ssorted,
                       float* __restrict__ nrm) {
    int e = blockIdx.x * blockDim.x + threadIdx.x;
    if (e >= N_EDGES) return;
    int s = src[e], d = dst[e];
    int pos = atomicAdd(&woff[d], 1);
    ssorted[pos] = s;
    nrm[pos] = dis[s] * ew[e] * dis[d];
}

// ---------------- GEMM1: xw1[N,64] = x[N,256] @ W1[256,64] ----------------
// W1 staged in 32x64 chunks (8KB) to keep LDS ~17KB -> high occupancy.
__global__ __launch_bounds__(256) void k_gemm1(const float* __restrict__ x,
                                               const float* __restrict__ W1,
                                               float* __restrict__ xw1) {
    __shared__ float Ws[32 * H1DIM];   // 8KB chunk of W1
    __shared__ float As[32][68];       // 8.7KB, transposed x chunk, padded
    int t = threadIdx.x;
    int r0 = blockIdx.x * 64;
    float acc[4][4] = {};
    int tr = t >> 4, tc = t & 15;
    for (int kc = 0; kc < 8; ++kc) {
        __syncthreads();
        // stage W1 chunk: rows kc*32 .. kc*32+31
        for (int q = t; q < (32 * H1DIM) / 4; q += 256) {
            *(float4*)&Ws[q * 4] = *(const float4*)&W1[kc * 32 * H1DIM + q * 4];
        }
        // stage x chunk (64 rows x 32 k), transposed into As[k][row]
        for (int q = t; q < 512; q += 256) {
            int row = q >> 3, kg = (q & 7) * 4;
            int gr = r0 + row;
            float4 v = make_float4(0.f, 0.f, 0.f, 0.f);
            if (gr < N_NODES)
                v = *(const float4*)&x[(size_t)gr * F_INPUT + kc * 32 + kg];
            As[kg + 0][row] = v.x; As[kg + 1][row] = v.y;
            As[kg + 2][row] = v.z; As[kg + 3][row] = v.w;
        }
        __syncthreads();
#pragma unroll
        for (int k = 0; k < 32; ++k) {
            float4 a = *(float4*)&As[k][tr * 4];
            float4 b = *(float4*)&Ws[k * H1DIM + tc * 4];
            float av[4] = {a.x, a.y, a.z, a.w};
            float bv[4] = {b.x, b.y, b.z, b.w};
#pragma unroll
            for (int i = 0; i < 4; ++i)
#pragma unroll
                for (int j = 0; j < 4; ++j)
                    acc[i][j] = fmaf(av[i], bv[j], acc[i][j]);
        }
    }
#pragma unroll
    for (int i = 0; i < 4; ++i) {
        int r = r0 + tr * 4 + i;
        if (r < N_NODES) {
            float4 v = make_float4(acc[i][0], acc[i][1], acc[i][2], acc[i][3]);
            *(float4*)&xw1[(size_t)r * H1DIM + tc * 4] = v;
        }
    }
}

// ---------------- agg1: h1 = relu(Ahat @ xw1 + b1), one wave per node ----------------
__global__ __launch_bounds__(256) void k_agg1(const float* __restrict__ xw1,
                                              const float* __restrict__ dis,
                                              const int* __restrict__ rowptr,
                                              const int* __restrict__ ssorted,
                                              const float* __restrict__ nrm,
                                              const float* __restrict__ b1,
                                              float* __restrict__ h1) {
    int wave = threadIdx.x >> 6, lane = threadIdx.x & 63;
    int n = blockIdx.x * 4 + wave;
    if (n >= N_NODES) return;
    float dn = dis[n];
    float acc = dn * dn * xw1[(size_t)n * H1DIM + lane];
    int beg = rowptr[n], end = rowptr[n + 1];
    int i = beg;
    for (; i + 1 < end; i += 2) {
        int s0 = ssorted[i], s1 = ssorted[i + 1];
        float m0 = nrm[i], m1 = nrm[i + 1];
        float v0 = xw1[(size_t)s0 * H1DIM + lane];
        float v1 = xw1[(size_t)s1 * H1DIM + lane];
        acc = fmaf(m0, v0, acc);
        acc = fmaf(m1, v1, acc);
    }
    if (i < end)
        acc = fmaf(nrm[i], xw1[(size_t)ssorted[i] * H1DIM + lane], acc);
    acc += b1[lane];
    h1[(size_t)n * H1DIM + lane] = fmaxf(acc, 0.0f);
}

// ---------------- GEMM2: xw2[N,128] = h1[N,64] @ W2[64,128] ----------------
__global__ __launch_bounds__(256) void k_gemm2(const float* __restrict__ h1,
                                               const float* __restrict__ W2,
                                               float* __restrict__ xw2) {
    __shared__ float Ws[H1DIM * H2DIM];  // 32KB
    __shared__ float As[64][68];         // 17.4KB
    int t = threadIdx.x;
    int r0 = blockIdx.x * 64;
    for (int q = t; q < (H1DIM * H2DIM) / 4; q += 256) {
        *(float4*)&Ws[q * 4] = *(const float4*)&W2[q * 4];
    }
    for (int q = t; q < 1024; q += 256) {
        int row = q >> 4, kg = (q & 15) * 4;
        int gr = r0 + row;
        float4 v = make_float4(0.f, 0.f, 0.f, 0.f);
        if (gr < N_NODES)
            v = *(const float4*)&h1[(size_t)gr * H1DIM + kg];
        As[kg + 0][row] = v.x; As[kg + 1][row] = v.y;
        As[kg + 2][row] = v.z; As[kg + 3][row] = v.w;
    }
    __syncthreads();
    float acc[4][8] = {};
    int tr = t >> 4, tc = t & 15;
#pragma unroll 8
    for (int k = 0; k < 64; ++k) {
        float4 a = *(float4*)&As[k][tr * 4];
        float4 b0 = *(float4*)&Ws[k * H2DIM + tc * 8];
        float4 b1v = *(float4*)&Ws[k * H2DIM + tc * 8 + 4];
        float av[4] = {a.x, a.y, a.z, a.w};
        float bv[8] = {b0.x, b0.y, b0.z, b0.w, b1v.x, b1v.y, b1v.z, b1v.w};
#pragma unroll
        for (int i = 0; i < 4; ++i)
#pragma unroll
            for (int j = 0; j < 8; ++j)
                acc[i][j] = fmaf(av[i], bv[j], acc[i][j]);
    }
#pragma unroll
    for (int i = 0; i < 4; ++i) {
        int r = r0 + tr * 4 + i;
        if (r < N_NODES) {
            float4 v0 = make_float4(acc[i][0], acc[i][1], acc[i][2], acc[i][3]);
            float4 v1 = make_float4(acc[i][4], acc[i][5], acc[i][6], acc[i][7]);
            *(float4*)&xw2[(size_t)r * H2DIM + tc * 8] = v0;
            *(float4*)&xw2[(size_t)r * H2DIM + tc * 8 + 4] = v1;
        }
    }
}

// ---------------- agg2 + readout: only the 4096 join rows ----------------
__global__ __launch_bounds__(256) void k_agg2(const float* __restrict__ xw2,
                                              const float* __restrict__ dis,
                                              const int* __restrict__ rowptr,
                                              const int* __restrict__ ssorted,
                                              const float* __restrict__ nrm,
                                              const float* __restrict__ b2,
                                              const int* __restrict__ join,
                                              const float* __restrict__ Wl,
                                              const float* __restrict__ bl,
                                              float* __restrict__ out) {
    int wave = threadIdx.x >> 6, lane = threadIdx.x & 63;
    int j = blockIdx.x * 4 + wave;
    if (j >= BATCH) return;
    int n = join[j];
    float dn = dis[n];
    float a0 = dn * dn * xw2[(size_t)n * H2DIM + lane];
    float a1 = dn * dn * xw2[(size_t)n * H2DIM + 64 + lane];
    int beg = rowptr[n], end = rowptr[n + 1];
    for (int i = beg; i < end; ++i) {
        int s = ssorted[i];
        float m = nrm[i];
        a0 = fmaf(m, xw2[(size_t)s * H2DIM + lane], a0);
        a1 = fmaf(m, xw2[(size_t)s * H2DIM + 64 + lane], a1);
    }
    a0 += b2[lane];
    a1 += b2[64 + lane];
    float p = a0 * Wl[lane] + a1 * Wl[64 + lane];
#pragma unroll
    for (int off = 32; off > 0; off >>= 1) p += __shfl_xor(p, off);
    if (lane == 0) out[j] = 1.0f / (1.0f + expf(-(p + bl[0])));
}

extern "C" void kernel_launch(void* const* d_in, const int* in_sizes, int n_in,
                              void* d_out, int out_size, void* d_ws, size_t ws_size,
                              hipStream_t stream) {
    const float* x   = (const float*)d_in[0];
    const int*   ei  = (const int*)d_in[1];
    const int*   jix = (const int*)d_in[2];
    const float* ew  = (const float*)d_in[3];
    const float* W1  = (const float*)d_in[4];
    const float* b1  = (const float*)d_in[5];
    const float* W2  = (const float*)d_in[6];
    const float* b2  = (const float*)d_in[7];
    const float* Wl  = (const float*)d_in[8];
    const float* bl  = (const float*)d_in[9];
    float* out = (float*)d_out;
    const int* srcp = ei;
    const int* dstp = ei + N_EDGES;

    char* p = (char*)d_ws;
    auto alloc = [&](size_t bytes) {
        char* r = p;
        p += (bytes + 255) & ~(size_t)255;
        return r;
    };
    float* dis     = (float*)alloc((size_t)N_NODES * 4);
    int*   cnt     = (int*)alloc((size_t)(N_NODES + 1) * 4);   // reused as woff
    int*   rowptr  = (int*)alloc((size_t)(N_NODES + 1) * 4);
    int*   bsums   = (int*)alloc(1024 * 4);
    int*   ssorted = (int*)alloc((size_t)N_EDGES * 4);
    float* nrm     = (float*)alloc((size_t)N_EDGES * 4);
    float* xw1     = (float*)alloc((size_t)N_NODES * H1DIM * 4);
    float* h1      = (float*)alloc((size_t)N_NODES * H1DIM * 4);
    float* xw2     = (float*)alloc((size_t)N_NODES * H2DIM * 4);

    hipMemsetAsync(dis, 0, (size_t)N_NODES * 4, stream);
    hipMemsetAsync(cnt, 0, (size_t)(N_NODES + 1) * 4, stream);

    k_deg<<<(N_EDGES + 255) / 256, 256, 0, stream>>>(dstp, ew, dis, cnt);
    k_dis<<<(N_NODES + 255) / 256, 256, 0, stream>>>(dis);
    int nb = (N_NODES + 1023) / 1024;
    k_scan1<<<nb, 256, 0, stream>>>(cnt, rowptr, bsums);
    k_scan2<<<1, 64, 0, stream>>>(bsums, nb);
    k_scan3<<<(N_NODES + 255) / 256, 256, 0, stream>>>(rowptr, bsums, cnt /*woff*/);
    k_fill<<<(N_EDGES + 255) / 256, 256, 0, stream>>>(srcp, dstp, ew, dis, cnt /*woff*/, ssorted, nrm);
    k_gemm1<<<(N_NODES + 63) / 64, 256, 0, stream>>>(x, W1, xw1);
    k_agg1<<<(N_NODES + 3) / 4, 256, 0, stream>>>(xw1, dis, rowptr, ssorted, nrm, b1, h1);
    k_gemm2<<<(N_NODES + 63) / 64, 256, 0, stream>>>(h1, W2, xw2);
    k_agg2<<<(BATCH + 3) / 4, 256, 0, stream>>>(xw2, dis, rowptr, ssorted, nrm, b2, jix, Wl, bl, out);
}

// Round 4
// 509.430 us; speedup vs baseline: 1.2172x; 1.2172x over previous
//
#include <hip/hip_runtime.h>
#include <hip/hip_bf16.h>

#define N_NODES 100000
#define N_EDGES 1600000
#define F_INPUT 256
#define H1DIM 64
#define H2DIM 128
#define BATCH 4096

// ---------------- degree: ONE packed 64-bit atomic per edge ----------------
// bits 40..63: edge count; bits 0..39: sum(ew) in 2^-32 fixed point.
// max degree ~45 (random 1.6M->100K), sum < 64 -> fits 40 bits with scale 2^32.
__global__ void k_deg(const int* __restrict__ dst, const float* __restrict__ ew,
                      unsigned long long* __restrict__ degp) {
    int e = blockIdx.x * blockDim.x + threadIdx.x;
    if (e >= N_EDGES) return;
    int d = dst[e];
    unsigned long long fx = (unsigned long long)(ew[e] * 4294967296.0f);
    atomicAdd(&degp[d], (1ULL << 40) | fx);
}

__global__ void k_dis(const unsigned long long* __restrict__ degp,
                      float* __restrict__ dis, int* __restrict__ cnt) {
    int n = blockIdx.x * blockDim.x + threadIdx.x;
    if (n >= N_NODES) return;
    unsigned long long p = degp[n];
    cnt[n] = (int)(p >> 40);
    float degw = (float)((double)(p & ((1ULL << 40) - 1)) * (1.0 / 4294967296.0));
    dis[n] = rsqrtf(degw + 1.0f);  // self-loop weight 1
}

// ---------------- prefix scan (3 kernels) ----------------
__global__ void k_scan1(const int* __restrict__ cnt, int* __restrict__ rowptr,
                        int* __restrict__ bsums) {
    __shared__ int sh[256];
    int base = blockIdx.x * 1024;
    int t = threadIdx.x;
    int i0 = base + t * 4;
    int v[4];
#pragma unroll
    for (int j = 0; j < 4; ++j) {
        int i = i0 + j;
        v[j] = (i < N_NODES) ? cnt[i] : 0;
    }
    int s = v[0] + v[1] + v[2] + v[3];
    sh[t] = s;
    __syncthreads();
    for (int off = 1; off < 256; off <<= 1) {
        int xv = (t >= off) ? sh[t - off] : 0;
        __syncthreads();
        sh[t] += xv;
        __syncthreads();
    }
    int ex = sh[t] - s;
    if (t == 255) bsums[blockIdx.x] = sh[255];
    int run = ex;
#pragma unroll
    for (int j = 0; j < 4; ++j) {
        int i = i0 + j;
        if (i < N_NODES) rowptr[i] = run;
        run += v[j];
    }
}

__global__ void k_scan2(int* __restrict__ bsums, int nb) {
    if (blockIdx.x == 0 && threadIdx.x == 0) {
        int run = 0;
        for (int i = 0; i < nb; ++i) { int v = bsums[i]; bsums[i] = run; run += v; }
    }
}

__global__ void k_scan3(int* __restrict__ rowptr, const int* __restrict__ bsums,
                        int* __restrict__ woff) {
    int i = blockIdx.x * blockDim.x + threadIdx.x;
    if (i == 0) rowptr[N_NODES] = N_EDGES;
    if (i >= N_NODES) return;
    int v = rowptr[i] + bsums[i >> 10];
    rowptr[i] = v;
    woff[i] = v;
}

// ---------------- CSR fill: packed int2 record (src, norm) ----------------
__global__ void k_fill(const int* __restrict__ src, const int* __restrict__ dst,
                       const float* __restrict__ ew, const float* __restrict__ dis,
                       int* __restrict__ woff, int2* __restrict__ erec) {
    int e = blockIdx.x * blockDim.x + threadIdx.x;
    if (e >= N_EDGES) return;
    int s = src[e], d = dst[e];
    int pos = atomicAdd(&woff[d], 1);
    float nr = dis[s] * ew[e] * dis[d];
    erec[pos] = make_int2(s, __float_as_int(nr));
}

// ---------------- GEMM1: xw1[N,64] = x[N,256] @ W1[256,64] ----------------
__global__ __launch_bounds__(256) void k_gemm1(const float* __restrict__ x,
                                               const float* __restrict__ W1,
                                               float* __restrict__ xw1) {
    __shared__ float Ws[32 * H1DIM];   // 8KB chunk of W1
    __shared__ float As[32][68];       // transposed x chunk, padded
    int t = threadIdx.x;
    int r0 = blockIdx.x * 64;
    float acc[4][4] = {};
    int tr = t >> 4, tc = t & 15;
    for (int kc = 0; kc < 8; ++kc) {
        __syncthreads();
        for (int q = t; q < (32 * H1DIM) / 4; q += 256) {
            *(float4*)&Ws[q * 4] = *(const float4*)&W1[kc * 32 * H1DIM + q * 4];
        }
        for (int q = t; q < 512; q += 256) {
            int row = q >> 3, kg = (q & 7) * 4;
            int gr = r0 + row;
            float4 v = make_float4(0.f, 0.f, 0.f, 0.f);
            if (gr < N_NODES)
                v = *(const float4*)&x[(size_t)gr * F_INPUT + kc * 32 + kg];
            As[kg + 0][row] = v.x; As[kg + 1][row] = v.y;
            As[kg + 2][row] = v.z; As[kg + 3][row] = v.w;
        }
        __syncthreads();
#pragma unroll
        for (int k = 0; k < 32; ++k) {
            float4 a = *(float4*)&As[k][tr * 4];
            float4 b = *(float4*)&Ws[k * H1DIM + tc * 4];
            float av[4] = {a.x, a.y, a.z, a.w};
            float bv[4] = {b.x, b.y, b.z, b.w};
#pragma unroll
            for (int i = 0; i < 4; ++i)
#pragma unroll
                for (int j = 0; j < 4; ++j)
                    acc[i][j] = fmaf(av[i], bv[j], acc[i][j]);
        }
    }
#pragma unroll
    for (int i = 0; i < 4; ++i) {
        int r = r0 + tr * 4 + i;
        if (r < N_NODES) {
            float4 v = make_float4(acc[i][0], acc[i][1], acc[i][2], acc[i][3]);
            *(float4*)&xw1[(size_t)r * H1DIM + tc * 4] = v;
        }
    }
}

// ---------------- agg1: h1 = relu(Ahat @ xw1 + b1), one wave per node ----------------
__global__ __launch_bounds__(256) void k_agg1(const float* __restrict__ xw1,
                                              const float* __restrict__ dis,
                                              const int* __restrict__ rowptr,
                                              const int2* __restrict__ erec,
                                              const float* __restrict__ b1,
                                              float* __restrict__ h1) {
    int wave = threadIdx.x >> 6, lane = threadIdx.x & 63;
    int n = blockIdx.x * 4 + wave;
    if (n >= N_NODES) return;
    float dn = dis[n];
    float acc = dn * dn * xw1[(size_t)n * H1DIM + lane];
    int beg = rowptr[n], end = rowptr[n + 1];
    int i = beg;
    for (; i + 1 < end; i += 2) {
        int2 r0 = erec[i], r1 = erec[i + 1];
        float v0 = xw1[(size_t)r0.x * H1DIM + lane];
        float v1 = xw1[(size_t)r1.x * H1DIM + lane];
        acc = fmaf(__int_as_float(r0.y), v0, acc);
        acc = fmaf(__int_as_float(r1.y), v1, acc);
    }
    if (i < end) {
        int2 r = erec[i];
        acc = fmaf(__int_as_float(r.y), xw1[(size_t)r.x * H1DIM + lane], acc);
    }
    acc += b1[lane];
    h1[(size_t)n * H1DIM + lane] = fmaxf(acc, 0.0f);
}

// ---------------- GEMM2: xw2[N,128] = h1[N,64] @ W2[64,128] ----------------
__global__ __launch_bounds__(256) void k_gemm2(const float* __restrict__ h1,
                                               const float* __restrict__ W2,
                                               float* __restrict__ xw2) {
    __shared__ float Ws[H1DIM * H2DIM];  // 32KB
    __shared__ float As[64][68];         // 17.4KB
    int t = threadIdx.x;
    int r0 = blockIdx.x * 64;
    for (int q = t; q < (H1DIM * H2DIM) / 4; q += 256) {
        *(float4*)&Ws[q * 4] = *(const float4*)&W2[q * 4];
    }
    for (int q = t; q < 1024; q += 256) {
        int row = q >> 4, kg = (q & 15) * 4;
        int gr = r0 + row;
        float4 v = make_float4(0.f, 0.f, 0.f, 0.f);
        if (gr < N_NODES)
            v = *(const float4*)&h1[(size_t)gr * H1DIM + kg];
        As[kg + 0][row] = v.x; As[kg + 1][row] = v.y;
        As[kg + 2][row] = v.z; As[kg + 3][row] = v.w;
    }
    __syncthreads();
    float acc[4][8] = {};
    int tr = t >> 4, tc = t & 15;
#pragma unroll 8
    for (int k = 0; k < 64; ++k) {
        float4 a = *(float4*)&As[k][tr * 4];
        float4 b0 = *(float4*)&Ws[k * H2DIM + tc * 8];
        float4 b1v = *(float4*)&Ws[k * H2DIM + tc * 8 + 4];
        float av[4] = {a.x, a.y, a.z, a.w};
        float bv[8] = {b0.x, b0.y, b0.z, b0.w, b1v.x, b1v.y, b1v.z, b1v.w};
#pragma unroll
        for (int i = 0; i < 4; ++i)
#pragma unroll
            for (int j = 0; j < 8; ++j)
                acc[i][j] = fmaf(av[i], bv[j], acc[i][j]);
    }
#pragma unroll
    for (int i = 0; i < 4; ++i) {
        int r = r0 + tr * 4 + i;
        if (r < N_NODES) {
            float4 v0 = make_float4(acc[i][0], acc[i][1], acc[i][2], acc[i][3]);
            float4 v1 = make_float4(acc[i][4], acc[i][5], acc[i][6], acc[i][7]);
            *(float4*)&xw2[(size_t)r * H2DIM + tc * 8] = v0;
            *(float4*)&xw2[(size_t)r * H2DIM + tc * 8 + 4] = v1;
        }
    }
}

// ---------------- agg2 + readout: only the 4096 join rows ----------------
__global__ __launch_bounds__(256) void k_agg2(const float* __restrict__ xw2,
                                              const float* __restrict__ dis,
                                              const int* __restrict__ rowptr,
                                              const int2* __restrict__ erec,
                                              const float* __restrict__ b2,
                                              const int* __restrict__ join,
                                              const float* __restrict__ Wl,
                                              const float* __restrict__ bl,
                                              float* __restrict__ out) {
    int wave = threadIdx.x >> 6, lane = threadIdx.x & 63;
    int j = blockIdx.x * 4 + wave;
    if (j >= BATCH) return;
    int n = join[j];
    float dn = dis[n];
    float a0 = dn * dn * xw2[(size_t)n * H2DIM + lane];
    float a1 = dn * dn * xw2[(size_t)n * H2DIM + 64 + lane];
    int beg = rowptr[n], end = rowptr[n + 1];
    for (int i = beg; i < end; ++i) {
        int2 r = erec[i];
        float m = __int_as_float(r.y);
        a0 = fmaf(m, xw2[(size_t)r.x * H2DIM + lane], a0);
        a1 = fmaf(m, xw2[(size_t)r.x * H2DIM + 64 + lane], a1);
    }
    a0 += b2[lane];
    a1 += b2[64 + lane];
    float p = a0 * Wl[lane] + a1 * Wl[64 + lane];
#pragma unroll
    for (int off = 32; off > 0; off >>= 1) p += __shfl_xor(p, off);
    if (lane == 0) out[j] = 1.0f / (1.0f + expf(-(p + bl[0])));
}

extern "C" void kernel_launch(void* const* d_in, const int* in_sizes, int n_in,
                              void* d_out, int out_size, void* d_ws, size_t ws_size,
                              hipStream_t stream) {
    const float* x   = (const float*)d_in[0];
    const int*   ei  = (const int*)d_in[1];
    const int*   jix = (const int*)d_in[2];
    const float* ew  = (const float*)d_in[3];
    const float* W1  = (const float*)d_in[4];
    const float* b1  = (const float*)d_in[5];
    const float* W2  = (const float*)d_in[6];
    const float* b2  = (const float*)d_in[7];
    const float* Wl  = (const float*)d_in[8];
    const float* bl  = (const float*)d_in[9];
    float* out = (float*)d_out;
    const int* srcp = ei;
    const int* dstp = ei + N_EDGES;

    char* p = (char*)d_ws;
    auto alloc = [&](size_t bytes) {
        char* r = p;
        p += (bytes + 255) & ~(size_t)255;
        return r;
    };
    unsigned long long* degp = (unsigned long long*)alloc((size_t)N_NODES * 8);
    float* dis     = (float*)alloc((size_t)N_NODES * 4);
    int*   cnt     = (int*)alloc((size_t)(N_NODES + 1) * 4);   // reused as woff
    int*   rowptr  = (int*)alloc((size_t)(N_NODES + 1) * 4);
    int*   bsums   = (int*)alloc(1024 * 4);
    int2*  erec    = (int2*)alloc((size_t)N_EDGES * 8);
    float* xw1     = (float*)alloc((size_t)N_NODES * H1DIM * 4);
    float* h1      = (float*)alloc((size_t)N_NODES * H1DIM * 4);
    float* xw2     = (float*)alloc((size_t)N_NODES * H2DIM * 4);

    hipMemsetAsync(degp, 0, (size_t)N_NODES * 8, stream);

    k_deg<<<(N_EDGES + 255) / 256, 256, 0, stream>>>(dstp, ew, degp);
    k_dis<<<(N_NODES + 255) / 256, 256, 0, stream>>>(degp, dis, cnt);
    int nb = (N_NODES + 1023) / 1024;
    k_scan1<<<nb, 256, 0, stream>>>(cnt, rowptr, bsums);
    k_scan2<<<1, 64, 0, stream>>>(bsums, nb);
    k_scan3<<<(N_NODES + 255) / 256, 256, 0, stream>>>(rowptr, bsums, cnt /*woff*/);
    k_fill<<<(N_EDGES + 255) / 256, 256, 0, stream>>>(srcp, dstp, ew, dis, cnt /*woff*/, erec);
    k_gemm1<<<(N_NODES + 63) / 64, 256, 0, stream>>>(x, W1, xw1);
    k_agg1<<<(N_NODES + 3) / 4, 256, 0, stream>>>(xw1, dis, rowptr, erec, b1, h1);
    k_gemm2<<<(N_NODES + 63) / 64, 256, 0, stream>>>(h1, W2, xw2);
    k_agg2<<<(BATCH + 3) / 4, 256, 0, stream>>>(xw2, dis, rowptr, erec, b2, jix, Wl, bl, out);
}